// Round 7
// baseline (2266.788 us; speedup 1.0000x reference)
//
#include <hip/hip_runtime.h>

#define NN 512
#define NM1 511
#define PCT(r, j) pcT[(r) * 13 + (j)]

// X-macro helpers: T4x16(X) expands X(K,M) for K=0..3, M=0..15
#define T16(X, K) X(K,0) X(K,1) X(K,2) X(K,3) X(K,4) X(K,5) X(K,6) X(K,7) \
                  X(K,8) X(K,9) X(K,10) X(K,11) X(K,12) X(K,13) X(K,14) X(K,15)
#define T4x16(X) T16(X,0) T16(X,1) T16(X,2) T16(X,3)
#define T16S(X) X(0) X(1) X(2) X(3) X(4) X(5) X(6) X(7) \
                X(8) X(9) X(10) X(11) X(12) X(13) X(14) X(15)

// One block per matrix (1024 blocks). Blocked LU, panel r=8, implicit partial
// pivoting. Tile: rows {L,L+64,L+128,L+192} x cols [16w,16w+16) as 64 named
// scalars (r6 model: tile -> 64 AGPRs, arch cap 64; memory spills were the
// EXTRA per-thread arrays parr/pcrow/u overflowing the 128-reg total budget).
// This round: register diet — parr[8] -> 4-bit dead4 mask, pcrow dropped
// (LDS RMW), quad-at-a-time trailing update, no unroll on the step loop.
__global__ __launch_bounds__(1024) void det_lu_kernel(
    const float* __restrict__ x,
    const float* __restrict__ F,
    float* __restrict__ out) {
  __shared__ __align__(16) float pcT[256 * 13];   // panel cols, row-major pad 13
  __shared__ __align__(16) float lbuf[8 * 256];   // multipliers per step
  __shared__ __align__(16) float Ubuf[8 * 260];   // final pivot rows (pad 260)
  __shared__ __align__(16) float araw[8 * 260];   // raw pivot rows
  __shared__ float livef[256];
  __shared__ int   perm[256];
  __shared__ int   upbuf[256];
  __shared__ int   dnbuf[256];
  __shared__ int   wavecnt[8];
  __shared__ int   totinv;

  const int tid = threadIdx.x;
  const int L   = tid & 63;       // lane
  const int w   = tid >> 6;       // wave

  const float* xrow = x + (size_t)blockIdx.x * NN;

  // ---- rank the +/-1 pattern: up = x>0 positions, dn = x<=0 positions
  bool pos = false;
  unsigned long long mask = 0;
  if (tid < NN) {
    float xv = xrow[tid];
    pos = xv > 0.0f;
    mask = __ballot(pos);
    if (L == 0) wavecnt[w] = __popcll(mask);
  }
  if (tid == 0) totinv = 0;
  if (tid < 256) livef[tid] = 1.0f;
  __syncthreads();
  if (tid < NN) {
    int base = 0;
    for (int i = 0; i < w; i++) base += wavecnt[i];
    int pbelow = __popcll(mask & ((1ull << L) - 1ull));
    if (pos) upbuf[base + pbelow] = tid;
    else     dnbuf[(64 * w - base) + (L - pbelow)] = tid;
  }
  __syncthreads();

  // ---- gather tile into 64 named scalars: aK_M = sub[L+64K][16w+M]
#define DECLC(M) const int cg##M = dnbuf[16 * w + (M)];
  T16S(DECLC)
  const int rg0 = upbuf[L];
  const int rg1 = upbuf[L + 64];
  const int rg2 = upbuf[L + 128];
  const int rg3 = upbuf[L + 192];
#define DECLA(K, M)                                                         \
  float a##K##_##M = (cg##M == rg##K)                                       \
      ? 0.0f                                                                \
      : F[(size_t)rg##K * NM1 + cg##M - (cg##M > rg##K ? 1 : 0)];
  T4x16(DECLA)

  // ---- seed panel 0: wave 0 writes PCT[row][0..7]
  if (w == 0) {
#define S0(K, M) if ((M) < 8) PCT(L + 64 * (K), (M)) = a##K##_##M;
    T4x16(S0)
  }
  double det = 1.0;
  bool mylive = true;          // row-thread's own-row liveness (tid>=768)
  __syncthreads();

  // ---- panel loop
  for (int P = 0; P < 32; P++) {
    unsigned dead4 = 0u;   // bit k: my row L+64k pivoted in THIS panel
                           // (prior panels: PCT seeded to 0 via livef)

    // -------- 8 column-steps, ONE barrier each --------
#pragma unroll 1
    for (int s = 0; s < 8; s++) {
      // search: all threads, redundant
      unsigned key = 0u;
#pragma unroll
      for (int k = 0; k < 4; k++) {
        int rho = L + 64 * k;
        float v = PCT(rho, s);
        unsigned b = __float_as_uint(fabsf(v)) & 0xFFFFFF00u;
        unsigned kq = ((dead4 >> k) & 1u) ? 0u : (b | (unsigned)rho);
        key = key > kq ? key : kq;
      }
#pragma unroll
      for (int off = 32; off; off >>= 1) {
        unsigned o = (unsigned)__shfl_xor((int)key, off);
        key = key > o ? key : o;
      }
      const int p = (int)(key & 255u);
      if ((p & 63) == L) dead4 |= 1u << (p >> 6);
      const float piv = PCT(p, s);   // nobody writes col s this step
      det *= (double)piv;

      if (tid >= 768) {              // row-thread work (LDS RMW, no reg cache)
        const int rr = tid - 768;
        const float invp = 1.0f / piv;
        const float ps = PCT(rr, s);
        float l = (mylive && rr != p) ? ps * invp : 0.0f;
        lbuf[s * 256 + rr] = l;
        if (rr == p) { mylive = false; livef[rr] = 0.0f; perm[P * 8 + s] = p; }
        for (int j = s + 1; j < 8; j++) {
          float uj = PCT(p, j);      // pivot row: benign same-value rewrite
          PCT(rr, j) = fmaf(-l, uj, PCT(rr, j));
        }
      }
      // raw pivot-row stash for the U-solve (live-col waves only)
      if ((2 * w + 1 > P) && L == (p & 63)) {
        const int kp = p >> 6;
        const int sb = s * 260 + 16 * w;
#define ST(K, M) if (kp == (K)) araw[sb + (M)] = a##K##_##M;
        T4x16(ST)
      }
      __syncthreads();
    }

    // -------- U-solve: U[t][j] = araw[t][j] - sum_{s<t} l_s[p_t]*U[s][j]
    if (tid < 256) {
      const int j = tid;
      float u[8];
#pragma unroll
      for (int t = 0; t < 8; t++) {
        int pt = perm[P * 8 + t];
        float acc = araw[t * 260 + j];
#pragma unroll
        for (int s2 = 0; s2 < t; s2++) acc = fmaf(-lbuf[s2 * 256 + pt], u[s2], acc);
        u[t] = acc;
        Ubuf[t * 260 + j] = acc;
      }
    }
    __syncthreads();

    // -------- rank-8 trailing update (quad at a time) + seed next panel ----
#define TUROW(K, A, B, C, D)                                                \
    a##K##_##A = fmaf(-lk##K, uq.x, a##K##_##A);                            \
    a##K##_##B = fmaf(-lk##K, uq.y, a##K##_##B);                            \
    a##K##_##C = fmaf(-lk##K, uq.z, a##K##_##C);                            \
    a##K##_##D = fmaf(-lk##K, uq.w, a##K##_##D);
#define TUQ(A, B, C, D)                                                     \
    TUROW(0, A, B, C, D) TUROW(1, A, B, C, D)                               \
    TUROW(2, A, B, C, D) TUROW(3, A, B, C, D)
    if (2 * w + 1 > P) {
      for (int t = 0; t < 8; t++) {
        const int lb = t * 256 + L;
        const float lk0 = lbuf[lb];
        const float lk1 = lbuf[lb + 64];
        const float lk2 = lbuf[lb + 128];
        const float lk3 = lbuf[lb + 192];
        const float* ub = &Ubuf[t * 260 + 16 * w];
        { const float4 uq = *reinterpret_cast<const float4*>(ub + 0);
          TUQ(0, 1, 2, 3) }
        { const float4 uq = *reinterpret_cast<const float4*>(ub + 4);
          TUQ(4, 5, 6, 7) }
        { const float4 uq = *reinterpret_cast<const float4*>(ub + 8);
          TUQ(8, 9, 10, 11) }
        { const float4 uq = *reinterpret_cast<const float4*>(ub + 12);
          TUQ(12, 13, 14, 15) }
      }
    }
    {
      const int wstar = (P + 1) >> 1, h = (P + 1) & 1;
      if (P < 31 && w == wstar) {
        const float lv0 = livef[L];
        const float lv1 = livef[L + 64];
        const float lv2 = livef[L + 128];
        const float lv3 = livef[L + 192];
        if (h == 0) {
#define SE0(K, M) if ((M) < 8) PCT(L + 64 * (K), (M)) = a##K##_##M * lv##K;
          T4x16(SE0)
        } else {
#define SE1(K, M) if ((M) >= 8) PCT(L + 64 * (K), (M) - 8) = a##K##_##M * lv##K;
          T4x16(SE1)
        }
      }
    }
    __syncthreads();
  }

  // ---- permutation parity via parallel inversion count (verified in r2)
  int myinv = 0;
  {
    const int i0 = tid & 255;
    const int cbase = (tid >> 8) * 64;
    const int pi = perm[i0];
#pragma unroll 8
    for (int j = 0; j < 64; j++) {
      int jj = cbase + j;
      if (jj > i0 && perm[jj] < pi) myinv++;
    }
  }
#pragma unroll
  for (int off = 32; off; off >>= 1) myinv += __shfl_xor(myinv, off);
  if (L == 0) atomicAdd(&totinv, myinv);
  __syncthreads();
  if (tid == 0) out[blockIdx.x] = (float)((totinv & 1) ? -det : det);
}

extern "C" void kernel_launch(void* const* d_in, const int* in_sizes, int n_in,
                              void* d_out, int out_size, void* d_ws, size_t ws_size,
                              hipStream_t stream) {
  const float* x = (const float*)d_in[0];   // (1024, 512) fp32
  const float* F = (const float*)d_in[1];   // (512*512-512,) fp32
  float* out = (float*)d_out;               // (1024,) fp32
  const int B = out_size;                   // 1024
  hipLaunchKernelGGL(det_lu_kernel, dim3(B), dim3(1024), 0, stream, x, F, out);
}